// Round 1
// baseline (782.813 us; speedup 1.0000x reference)
//
#include <hip/hip_runtime.h>
#include <hip/hip_bf16.h>
#include <stdint.h>
#include <stddef.h>

#define B_ 8
#define T_ 4096
#define D_ 1024
#define H_ 1024
#define M_ (B_*T_)      // 32768
#define N_ 3072
#define K_ 1024
#define CHUNK 64
#define NCHUNK (T_/CHUNK)  // 64

typedef __attribute__((ext_vector_type(8))) __bf16 bf16v8;
typedef __attribute__((ext_vector_type(4))) float f32x4;
typedef __attribute__((ext_vector_type(8))) unsigned short u16x8;

__device__ __forceinline__ unsigned short f2bf(float f) {
  union { float f; unsigned u; } x; x.f = f;
  return (unsigned short)((x.u + 0x7fffu + ((x.u >> 16) & 1u)) >> 16);
}

// ---------------- fp32 -> bf16 convert (vectorized, 8 elems/thread) ----------
__global__ __launch_bounds__(256) void cvt_f32_bf16(const float* __restrict__ src,
                                                    unsigned short* __restrict__ dst,
                                                    int n8) {
  int i = blockIdx.x * 256 + threadIdx.x;
  if (i >= n8) return;
  const float4* s = (const float4*)src;
  float4 a = s[i*2], b = s[i*2+1];
  u16x8 o;
  o[0]=f2bf(a.x); o[1]=f2bf(a.y); o[2]=f2bf(a.z); o[3]=f2bf(a.w);
  o[4]=f2bf(b.x); o[5]=f2bf(b.y); o[6]=f2bf(b.z); o[7]=f2bf(b.w);
  *(u16x8*)(dst + (size_t)i*8) = o;
}

// ---------------- bf16 GEMM: Z[m][n] = X[m][:] . W[n][:] + bias[n] ----------
// m97-structure: 128x128 tile, BK=64, 4 waves (2x2), 4x4 16x16x32 frags/wave,
// global_load_lds width=16 staging, 2 barriers per K-step.
#define BM 128
#define BN 128
#define BK 64

__global__ __launch_bounds__(256) void gemm_gates(
    const unsigned short* __restrict__ Abf,   // [M_][K_] bf16 bits
    const unsigned short* __restrict__ Bbf,   // [N_][K_] bf16 bits (W rows)
    const float* __restrict__ bf_, const float* __restrict__ bi_,
    const float* __restrict__ bh_,
    float* __restrict__ zf, float* __restrict__ zi, float* __restrict__ zh)
{
  __shared__ unsigned short As[BM*BK];
  __shared__ unsigned short Bs[BN*BK];

  int bid = blockIdx.x;
  int tn = bid % (N_/BN);          // fast: N tile (A-panel reuse in L2/L3)
  int tm = bid / (N_/BN);
  int tid = threadIdx.x;
  int lane = tid & 63, wid = tid >> 6;
  int wm = wid >> 1, wn = wid & 1;   // 2x2 waves, each 64x64 out

  const int m0 = tm*BM, n0 = tn*BN;
  f32x4 acc[4][4] = {};

  // staging: thread covers 16B at LDS byte off tid*16 + round*4096
  int srow = tid >> 3;          // 0..31
  int scol = (tid & 7) * 8;     // 0..56

  for (int k0 = 0; k0 < K_; k0 += BK) {
    #pragma unroll
    for (int r = 0; r < 4; ++r) {
      const unsigned short* g = Abf + (size_t)(m0 + r*32 + srow)*K_ + k0 + scol;
      __builtin_amdgcn_global_load_lds((const __attribute__((address_space(1))) void*)g,
          (__attribute__((address_space(3))) void*)(As + r*2048 + tid*8), 16, 0, 0);
    }
    #pragma unroll
    for (int r = 0; r < 4; ++r) {
      const unsigned short* g = Bbf + (size_t)(n0 + r*32 + srow)*K_ + k0 + scol;
      __builtin_amdgcn_global_load_lds((const __attribute__((address_space(1))) void*)g,
          (__attribute__((address_space(3))) void*)(Bs + r*2048 + tid*8), 16, 0, 0);
    }
    __syncthreads();

    #pragma unroll
    for (int kk = 0; kk < BK; kk += 32) {
      bf16v8 af[4], bg[4];
      int kcol = kk + (lane >> 4) * 8;
      int ar = wm*64 + (lane & 15);
      int br = wn*64 + (lane & 15);
      #pragma unroll
      for (int i = 0; i < 4; ++i)
        af[i] = *(const bf16v8*)(As + (ar + i*16)*BK + kcol);
      #pragma unroll
      for (int i = 0; i < 4; ++i)
        bg[i] = *(const bf16v8*)(Bs + (br + i*16)*BK + kcol);
      #pragma unroll
      for (int i = 0; i < 4; ++i)
        #pragma unroll
        for (int j = 0; j < 4; ++j)
          acc[i][j] = __builtin_amdgcn_mfma_f32_16x16x32_bf16(af[i], bg[j], acc[i][j], 0, 0, 0);
    }
    __syncthreads();
  }

  // epilogue: C/D layout col=lane&15, row=(lane>>4)*4+r  [m89-verified]
  int g = n0 >> 10;   // which gate plane (BN=128 tiles never straddle planes)
  float* Z = (g == 0) ? zf : (g == 1) ? zi : zh;
  const float* bias = (g == 0) ? bf_ : (g == 1) ? bi_ : bh_;
  int hcol0 = (n0 & 1023) + wn*64;
  int lc = lane & 15, lr = (lane >> 4) * 4;
  #pragma unroll
  for (int i = 0; i < 4; ++i) {
    #pragma unroll
    for (int j = 0; j < 4; ++j) {
      int col = hcol0 + j*16 + lc;
      float bv = bias[col];
      int mrow = m0 + wm*64 + i*16 + lr;
      #pragma unroll
      for (int r = 0; r < 4; ++r)
        Z[(size_t)(mrow + r)*H_ + col] = acc[i][j][r] + bv;
    }
  }
}

// ---------------- phase A: gates + per-chunk (A,S); f,v written in place ----
__global__ __launch_bounds__(256) void scan_phaseA(
    float* __restrict__ zf, float* __restrict__ zi, const float* __restrict__ zh,
    float* __restrict__ Aw, float* __restrict__ Sw)
{
  int blk = blockIdx.x;              // 8*64*4 = 2048
  int hb = blk & 3;
  int c  = (blk >> 2) & 63;
  int b  = blk >> 8;
  int h  = hb*256 + threadIdx.x;
  float Ap = 1.f, S = 0.f;
  size_t base = ((size_t)b*T_ + (size_t)c*CHUNK)*H_ + h;
  for (int t = 0; t < CHUNK; ++t) {
    size_t idx = base + (size_t)t*H_;
    float vzf = zf[idx], vzi = zi[idx], vzh = zh[idx];
    // diff = softplus(-zf) - softplus(-zi);  softplus(t)=max(t,0)+log1p(e^-|t|)
    float spf = fmaxf(-vzf, 0.f) + __logf(1.f + __expf(-fabsf(vzf)));
    float spi = fmaxf(-vzi, 0.f) + __logf(1.f + __expf(-fabsf(vzi)));
    float d   = spf - spi;
    float l1  = __logf(1.f + __expf(-fabsf(d)));
    float f   = __expf(-(fmaxf(d, 0.f) + l1));    // exp(-softplus(d))  = forget
    float iv  = __expf(-(fmaxf(-d, 0.f) + l1));   // exp(-softplus(-d)) = input
    float gv  = (vzh >= 0.f) ? (vzh + 0.5f) : 1.f/(1.f + __expf(-vzh));
    float v   = iv * gv;
    zf[idx] = f;        // in-place: plane now holds f
    zi[idx] = v;        // in-place: plane now holds v = i*g
    S  = fmaf(f, S, v);
    Ap *= f;
  }
  size_t widx = ((size_t)b*NCHUNK + c)*H_ + h;
  Aw[widx] = Ap;
  Sw[widx] = S;
}

// ---------------- phase B: cross-chunk prefix (tiny) ------------------------
__global__ __launch_bounds__(256) void scan_phaseB(
    const float* __restrict__ Aw, const float* __restrict__ Sw,
    const float* __restrict__ h0, float* __restrict__ Cw)
{
  int i = blockIdx.x*256 + threadIdx.x;    // b*H + h, 8192 total
  int b = i >> 10, h = i & 1023;
  float x0 = h0[i];
  float run = (x0 >= 0.f) ? (x0 + 0.5f) : 1.f/(1.f + __expf(-x0));  // g(h0)
  for (int c = 0; c < NCHUNK; ++c) {
    size_t idx = ((size_t)b*NCHUNK + c)*H_ + h;
    Cw[idx] = run;                       // carry INTO chunk c
    run = fmaf(Aw[idx], run, Sw[idx]);
  }
}

// ---------------- phase C: replay with carry, write h -----------------------
__global__ __launch_bounds__(256) void scan_phaseC(
    const float* __restrict__ fb, const float* __restrict__ vb,
    const float* __restrict__ Cw, float* __restrict__ out)
{
  int blk = blockIdx.x;
  int hb = blk & 3;
  int c  = (blk >> 2) & 63;
  int b  = blk >> 8;
  int h  = hb*256 + threadIdx.x;
  float hrun = Cw[((size_t)b*NCHUNK + c)*H_ + h];
  size_t base = ((size_t)b*T_ + (size_t)c*CHUNK)*H_ + h;
  for (int t = 0; t < CHUNK; ++t) {
    size_t idx = base + (size_t)t*H_;
    hrun = fmaf(fb[idx], hrun, vb[idx]);
    out[idx] = hrun;
  }
}

extern "C" void kernel_launch(void* const* d_in, const int* in_sizes, int n_in,
                              void* d_out, int out_size, void* d_ws, size_t ws_size,
                              hipStream_t stream) {
  const float* x   = (const float*)d_in[0];
  const float* h0  = (const float*)d_in[1];
  const float* W_f = (const float*)d_in[2];
  const float* b_f = (const float*)d_in[3];
  const float* W_i = (const float*)d_in[4];
  const float* b_i = (const float*)d_in[5];
  const float* W_h = (const float*)d_in[6];
  const float* b_h = (const float*)d_in[7];
  float* out = (float*)d_out;

  char* ws = (char*)d_ws;
  unsigned short* xb = (unsigned short*)ws;                         // 67.1 MB
  unsigned short* Wc = (unsigned short*)(ws + (size_t)M_*K_*2);     // 6.3 MB
  float* zf = (float*)(ws + (size_t)M_*K_*2 + (size_t)N_*K_*2);     // 134.2 MB
  float* zi = zf + (size_t)M_*H_;                                   // 134.2 MB
  float* Aw = zi + (size_t)M_*H_;                                   // 2 MB
  float* Sw = Aw + (size_t)B_*NCHUNK*H_;                            // 2 MB
  float* Cw = Sw + (size_t)B_*NCHUNK*H_;                            // 2 MB
  float* zh = out;  // zh plane lives in d_out, overwritten by h in phase C

  cvt_f32_bf16<<<M_*K_/8/256, 256, 0, stream>>>(x, xb, M_*K_/8);
  cvt_f32_bf16<<<H_*K_/8/256, 256, 0, stream>>>(W_f, Wc + (size_t)0*H_*K_, H_*K_/8);
  cvt_f32_bf16<<<H_*K_/8/256, 256, 0, stream>>>(W_i, Wc + (size_t)1*H_*K_, H_*K_/8);
  cvt_f32_bf16<<<H_*K_/8/256, 256, 0, stream>>>(W_h, Wc + (size_t)2*H_*K_, H_*K_/8);

  gemm_gates<<<(M_/BM)*(N_/BN), 256, 0, stream>>>(xb, Wc, b_f, b_i, b_h, zf, zi, zh);

  scan_phaseA<<<B_*NCHUNK*(H_/256), 256, 0, stream>>>(zf, zi, zh, Aw, Sw);
  scan_phaseB<<<B_*H_/256, 256, 0, stream>>>(Aw, Sw, h0, Cw);
  scan_phaseC<<<B_*NCHUNK*(H_/256), 256, 0, stream>>>(zf, zi, Cw, out);
}

// Round 3
// 626.360 us; speedup vs baseline: 1.2498x; 1.2498x over previous
//
#include <hip/hip_runtime.h>
#include <hip/hip_bf16.h>
#include <stdint.h>
#include <stddef.h>

#define B_ 8
#define T_ 4096
#define D_ 1024
#define H_ 1024
#define M_ (B_*T_)      // 32768
#define N_ 3072
#define K_ 1024
#define CHUNK 64
#define NCHUNK 64
#define NWG ((M_/256)*(N_/256))   // 1536

typedef __attribute__((ext_vector_type(8))) __bf16 bf16v8;
typedef __attribute__((ext_vector_type(4))) float f32x4;
typedef __attribute__((ext_vector_type(8))) unsigned short u16x8;

// LDS map (bytes): A regions at 0, B at 65536.
// Each matrix: [slot(2)][q(2)][row(128)][64 bf16] -> region 16KB, slot 32KB.
#define REG_SZ 16384
#define SLOT_SZ 32768
#define BOFF 65536
#define LDS_BYTES 131072

#define FENCE() asm volatile("" ::: "memory")
#define SBAR()  __builtin_amdgcn_s_barrier()

__device__ __forceinline__ unsigned short f2bf(float f) {
  union { float f; unsigned u; } x; x.f = f;
  return (unsigned short)((x.u + 0x7fffu + ((x.u >> 16) & 1u)) >> 16);
}

// ---------------- converts ----------------
__global__ __launch_bounds__(256) void cvt_x(const float* __restrict__ src,
                                             unsigned short* __restrict__ dst) {
  int i = blockIdx.x * 256 + threadIdx.x;      // 8 elems each
  const float4* s = (const float4*)src;
  float4 a = s[i*2], b = s[i*2+1];
  u16x8 o;
  o[0]=f2bf(a.x); o[1]=f2bf(a.y); o[2]=f2bf(a.z); o[3]=f2bf(a.w);
  o[4]=f2bf(b.x); o[5]=f2bf(b.y); o[6]=f2bf(b.z); o[7]=f2bf(b.w);
  *(u16x8*)(dst + (size_t)i*8) = o;
}

__global__ __launch_bounds__(256) void cvt_w(const float* __restrict__ w0,
                                             const float* __restrict__ w1,
                                             const float* __restrict__ w2,
                                             unsigned short* __restrict__ dst) {
  int i = blockIdx.x * 256 + threadIdx.x;      // 0..393215, 8 elems each
  int seg = i >> 17;                           // 131072 groups of 8 per matrix
  int off = i & 131071;
  const float* src = (seg == 0) ? w0 : (seg == 1) ? w1 : w2;
  const float4* s = (const float4*)src;
  float4 a = s[off*2], b = s[off*2+1];
  u16x8 o;
  o[0]=f2bf(a.x); o[1]=f2bf(a.y); o[2]=f2bf(a.z); o[3]=f2bf(a.w);
  o[4]=f2bf(b.x); o[5]=f2bf(b.y); o[6]=f2bf(b.z); o[7]=f2bf(b.w);
  *(u16x8*)(dst + (size_t)i*8) = o;
}

// ---------------- GEMM: 256x256 tile, BK=64, 8-phase counted-vmcnt ---------
// Half-tile H[k]: t=k>>2 (K-step), w=k&3: 0=A/q0, 1=B/q0, 2=B/q1, 3=A/q1.
// Issue schedule: prologue H[0..6]; phase P (=4t+q+1) issues H[P+6].
// Checkpoint vmcnt(6) at each step end (vmcnt(0) at t=14).
__device__ __forceinline__ void stage_half(int k, int m0, int n0,
    const unsigned short* Abf, const unsigned short* Bbf, char* smem, int tid) {
  if (k > 63) return;
  int t = k >> 2, w = k & 3;
  int q   = (w >= 2) ? 1 : 0;
  int isA = (w == 0 || w == 3);
  int slot = t & 1;
  int k0 = t * 64;
  const unsigned short* gbase = isA ? (Abf + (size_t)(m0 + q*128) * K_)
                                    : (Bbf + (size_t)(n0 + q*128) * K_);
  char* lbase = smem + (isA ? 0 : BOFF) + slot*SLOT_SZ + q*REG_SZ;
  #pragma unroll
  for (int l = 0; l < 2; ++l) {
    int o = tid*16 + l*8192;
    int row = o >> 7, cb = o & 127;
    int scb = cb ^ ((row & 7) << 4);           // inverse(=same) of read swizzle
    const unsigned short* g = gbase + (size_t)row * K_ + k0 + (scb >> 1);
    __builtin_amdgcn_global_load_lds((const __attribute__((address_space(1))) void*)g,
        (__attribute__((address_space(3))) void*)(lbase + o), 16, 0, 0);
  }
}

__device__ __forceinline__ bf16v8 ldsA(const char* smem, int slot, int q, int rr, int cb) {
  return *(const bf16v8*)(smem + slot*SLOT_SZ + q*REG_SZ + rr*128 + (cb ^ ((rr & 7) << 4)));
}
__device__ __forceinline__ bf16v8 ldsB(const char* smem, int slot, int q, int rr, int cb) {
  return *(const bf16v8*)(smem + BOFF + slot*SLOT_SZ + q*REG_SZ + rr*128 + (cb ^ ((rr & 7) << 4)));
}

__global__ __launch_bounds__(512, 2) void gemm_gates(
    const unsigned short* __restrict__ Abf,
    const unsigned short* __restrict__ Bbf,
    const float* __restrict__ bf_, const float* __restrict__ bi_,
    const float* __restrict__ bh_,
    float* __restrict__ zf, float* __restrict__ zi, float* __restrict__ zh)
{
  extern __shared__ char smem[];
  int tid = threadIdx.x;
  int bid = blockIdx.x;
  // bijective XCD swizzle (NWG % 8 == 0)
  int swz = (bid & 7) * (NWG/8) + (bid >> 3);
  int tn = swz % 12, tm = swz / 12;
  int m0 = tm*256, n0 = tn*256;
  int lane = tid & 63, wid = tid >> 6;
  int wm = wid >> 2, wn = wid & 3;             // 2 x 4 waves
  int lr = lane & 15, lhi = lane >> 4;
  int cbL = lhi * 16;                          // byte offset of k-slice (kk=0)

  f32x4 acc[8][4] = {};
  bf16v8 a0[4][2], b0[2][2], b1[2][2];

  #pragma unroll
  for (int k = 0; k < 7; ++k) stage_half(k, m0, n0, Abf, Bbf, smem, tid);
  asm volatile("s_waitcnt vmcnt(6)" ::: "memory");
  SBAR(); FENCE();

  for (int t = 0; t < 16; ++t) {
    int slot = t & 1;
    // ---- phase 0: quad (0,0) ----
    #pragma unroll
    for (int i = 0; i < 4; ++i)
      #pragma unroll
      for (int kk = 0; kk < 2; ++kk)
        a0[i][kk] = ldsA(smem, slot, 0, wm*64 + i*16 + lr, kk*64 + cbL);
    #pragma unroll
    for (int j = 0; j < 2; ++j)
      #pragma unroll
      for (int kk = 0; kk < 2; ++kk)
        b0[j][kk] = ldsB(smem, slot, 0, wn*32 + j*16 + lr, kk*64 + cbL);
    stage_half(4*t + 7, m0, n0, Abf, Bbf, smem, tid);
    FENCE(); SBAR(); FENCE();
    __builtin_amdgcn_s_setprio(1);
    #pragma unroll
    for (int i = 0; i < 4; ++i)
      #pragma unroll
      for (int j = 0; j < 2; ++j)
        #pragma unroll
        for (int kk = 0; kk < 2; ++kk)
          acc[i][j] = __builtin_amdgcn_mfma_f32_16x16x32_bf16(a0[i][kk], b0[j][kk], acc[i][j], 0, 0, 0);
    __builtin_amdgcn_s_setprio(0);
    FENCE(); SBAR(); FENCE();
    // ---- phase 1: quad (0,1) ----
    #pragma unroll
    for (int j = 0; j < 2; ++j)
      #pragma unroll
      for (int kk = 0; kk < 2; ++kk)
        b1[j][kk] = ldsB(smem, slot, 1, wn*32 + j*16 + lr, kk*64 + cbL);
    stage_half(4*t + 8, m0, n0, Abf, Bbf, smem, tid);
    FENCE(); SBAR(); FENCE();
    __builtin_amdgcn_s_setprio(1);
    #pragma unroll
    for (int i = 0; i < 4; ++i)
      #pragma unroll
      for (int j = 0; j < 2; ++j)
        #pragma unroll
        for (int kk = 0; kk < 2; ++kk)
          acc[i][2+j] = __builtin_amdgcn_mfma_f32_16x16x32_bf16(a0[i][kk], b1[j][kk], acc[i][2+j], 0, 0, 0);
    __builtin_amdgcn_s_setprio(0);
    FENCE(); SBAR(); FENCE();
    // ---- phase 2: quad (1,1) ----
    #pragma unroll
    for (int i = 0; i < 4; ++i)
      #pragma unroll
      for (int kk = 0; kk < 2; ++kk)
        a0[i][kk] = ldsA(smem, slot, 1, wm*64 + i*16 + lr, kk*64 + cbL);
    stage_half(4*t + 9, m0, n0, Abf, Bbf, smem, tid);
    FENCE(); SBAR(); FENCE();
    __builtin_amdgcn_s_setprio(1);
    #pragma unroll
    for (int i = 0; i < 4; ++i)
      #pragma unroll
      for (int j = 0; j < 2; ++j)
        #pragma unroll
        for (int kk = 0; kk < 2; ++kk)
          acc[4+i][2+j] = __builtin_amdgcn_mfma_f32_16x16x32_bf16(a0[i][kk], b1[j][kk], acc[4+i][2+j], 0, 0, 0);
    __builtin_amdgcn_s_setprio(0);
    FENCE(); SBAR(); FENCE();
    // ---- phase 3: quad (1,0) (operands in regs) ----
    stage_half(4*t + 10, m0, n0, Abf, Bbf, smem, tid);
    FENCE(); SBAR(); FENCE();
    __builtin_amdgcn_s_setprio(1);
    #pragma unroll
    for (int i = 0; i < 4; ++i)
      #pragma unroll
      for (int j = 0; j < 2; ++j)
        #pragma unroll
        for (int kk = 0; kk < 2; ++kk)
          acc[4+i][j] = __builtin_amdgcn_mfma_f32_16x16x32_bf16(a0[i][kk], b0[j][kk], acc[4+i][j], 0, 0, 0);
    __builtin_amdgcn_s_setprio(0);
    // ---- step checkpoint: counted vmcnt, never 0 until the tail ----
    if (t < 14) { asm volatile("s_waitcnt vmcnt(6)" ::: "memory"); }
    else        { asm volatile("s_waitcnt vmcnt(0)" ::: "memory"); }
    SBAR(); FENCE();
  }

  // epilogue
  int g = n0 >> 10;
  float* Z = (g == 0) ? zf : (g == 1) ? zi : zh;
  const float* bias = (g == 0) ? bf_ : (g == 1) ? bi_ : bh_;
  int ncol0 = n0 & 1023;
  #pragma unroll
  for (int qm = 0; qm < 2; ++qm)
    #pragma unroll
    for (int i = 0; i < 4; ++i)
      #pragma unroll
      for (int qn = 0; qn < 2; ++qn)
        #pragma unroll
        for (int j = 0; j < 2; ++j) {
          int col = ncol0 + qn*128 + wn*32 + j*16 + lr;
          float bv = bias[col];
          int row = m0 + qm*128 + wm*64 + i*16 + lhi*4;
          f32x4 a = acc[qm*4+i][qn*2+j];
          #pragma unroll
          for (int r = 0; r < 4; ++r)
            Z[(size_t)(row + r)*H_ + col] = a[r] + bv;
        }
}

// ---------------- phase A: gates + per-chunk (A,S); f,v packed bf16x2 -------
__device__ __forceinline__ void gate_eval(float vzf, float vzi, float vzh,
                                          float& f, float& v) {
  float spf = fmaxf(-vzf, 0.f) + __logf(1.f + __expf(-fabsf(vzf)));
  float spi = fmaxf(-vzi, 0.f) + __logf(1.f + __expf(-fabsf(vzi)));
  float d   = spf - spi;
  float l1  = __logf(1.f + __expf(-fabsf(d)));
  f = __expf(-(fmaxf(d, 0.f) + l1));
  float iv = __expf(-(fmaxf(-d, 0.f) + l1));
  float gv = (vzh >= 0.f) ? (vzh + 0.5f) : 1.f/(1.f + __expf(-vzh));
  v = iv * gv;
}

__global__ __launch_bounds__(256) void scan_phaseA(
    const float* zf, const float* __restrict__ zi,
    const float* __restrict__ zh, uint32_t* fv,   // fv aliases zf: no restrict
    float* __restrict__ Aw, float* __restrict__ Sw)
{
  int blk = blockIdx.x;                 // 512 = b*64 + c
  int c = blk & 63, b = blk >> 6;
  int h4 = threadIdx.x * 4;
  size_t base = ((size_t)b*T_ + (size_t)c*CHUNK)*H_ + h4;
  float Ap[4] = {1.f,1.f,1.f,1.f}, S[4] = {0.f,0.f,0.f,0.f};
  for (int t = 0; t < CHUNK; ++t) {
    size_t idx = base + (size_t)t*H_;
    float4 vf = *(const float4*)(zf + idx);
    float4 vi = *(const float4*)(zi + idx);
    float4 vh = *(const float4*)(zh + idx);
    uint32_t o[4];
    const float* pf = (const float*)&vf;
    const float* pi = (const float*)&vi;
    const float* ph = (const float*)&vh;
    #pragma unroll
    for (int u = 0; u < 4; ++u) {
      float f, v;
      gate_eval(pf[u], pi[u], ph[u], f, v);
      o[u] = (uint32_t)f2bf(f) | ((uint32_t)f2bf(v) << 16);
      S[u] = fmaf(f, S[u], v);
      Ap[u] *= f;
    }
    uint4 ov; ov.x = o[0]; ov.y = o[1]; ov.z = o[2]; ov.w = o[3];
    *(uint4*)(fv + idx) = ov;
  }
  size_t widx = ((size_t)b*NCHUNK + c)*H_ + h4;
  *(float4*)(Aw + widx) = make_float4(Ap[0], Ap[1], Ap[2], Ap[3]);
  *(float4*)(Sw + widx) = make_float4(S[0], S[1], S[2], S[3]);
}

// ---------------- phase B: cross-chunk prefix (tiny) ------------------------
__global__ __launch_bounds__(256) void scan_phaseB(
    const float* __restrict__ Aw, const float* __restrict__ Sw,
    const float* __restrict__ h0, float* __restrict__ Cw)
{
  int i = blockIdx.x*256 + threadIdx.x;    // 0..2047
  int b = i >> 8;
  int h4 = (i & 255) * 4;
  float4 x0 = *(const float4*)(h0 + (size_t)b*H_ + h4);
  float run[4];
  const float* px = (const float*)&x0;
  #pragma unroll
  for (int u = 0; u < 4; ++u)
    run[u] = (px[u] >= 0.f) ? (px[u] + 0.5f) : 1.f/(1.f + __expf(-px[u]));
  for (int c = 0; c < NCHUNK; ++c) {
    size_t idx = ((size_t)b*NCHUNK + c)*H_ + h4;
    *(float4*)(Cw + idx) = make_float4(run[0], run[1], run[2], run[3]);
    float4 av = *(const float4*)(Aw + idx);
    float4 sv = *(const float4*)(Sw + idx);
    const float* pa = (const float*)&av;
    const float* ps = (const float*)&sv;
    #pragma unroll
    for (int u = 0; u < 4; ++u) run[u] = fmaf(pa[u], run[u], ps[u]);
  }
}

// ---------------- phase C: replay with carry, write h -----------------------
__global__ __launch_bounds__(256) void scan_phaseC(
    const uint32_t* __restrict__ fv, const float* __restrict__ Cw,
    float* __restrict__ out)
{
  int blk = blockIdx.x;
  int c = blk & 63, b = blk >> 6;
  int h4 = threadIdx.x * 4;
  float4 cw = *(const float4*)(Cw + ((size_t)b*NCHUNK + c)*H_ + h4);
  float hh[4];
  const float* pc = (const float*)&cw;
  #pragma unroll
  for (int u = 0; u < 4; ++u) hh[u] = pc[u];
  size_t base = ((size_t)b*T_ + (size_t)c*CHUNK)*H_ + h4;
  for (int t = 0; t < CHUNK; ++t) {
    size_t idx = base + (size_t)t*H_;
    uint4 pk = *(const uint4*)(fv + idx);
    uint32_t w[4] = {pk.x, pk.y, pk.z, pk.w};
    #pragma unroll
    for (int u = 0; u < 4; ++u) {
      union { uint32_t u; float f; } cf, cv;
      cf.u = (w[u] & 0xffffu) << 16;
      cv.u = w[u] & 0xffff0000u;
      hh[u] = fmaf(cf.f, hh[u], cv.f);
    }
    *(float4*)(out + idx) = make_float4(hh[0], hh[1], hh[2], hh[3]);
  }
}

extern "C" void kernel_launch(void* const* d_in, const int* in_sizes, int n_in,
                              void* d_out, int out_size, void* d_ws, size_t ws_size,
                              hipStream_t stream) {
  const float* x   = (const float*)d_in[0];
  const float* h0  = (const float*)d_in[1];
  const float* W_f = (const float*)d_in[2];
  const float* b_f = (const float*)d_in[3];
  const float* W_i = (const float*)d_in[4];
  const float* b_i = (const float*)d_in[5];
  const float* W_h = (const float*)d_in[6];
  const float* b_h = (const float*)d_in[7];
  float* out = (float*)d_out;

  char* ws = (char*)d_ws;
  unsigned short* xb = (unsigned short*)ws;                         // 67.1 MB
  unsigned short* Wc = (unsigned short*)(ws + (size_t)M_*K_*2);     // 6.3 MB
  float* zf = (float*)(ws + (size_t)M_*K_*2 + (size_t)N_*K_*2);     // 134.2 MB
  float* zi = zf + (size_t)M_*H_;                                   // 134.2 MB
  float* Aw = zi + (size_t)M_*H_;                                   // 2 MB
  float* Sw = Aw + (size_t)B_*NCHUNK*H_;                            // 2 MB
  float* Cw = Sw + (size_t)B_*NCHUNK*H_;                            // 2 MB
  float* zh = out;                       // zh lives in d_out, overwritten by h
  uint32_t* fv = (uint32_t*)zf;          // packed f,v reuses zf plane in place

  static int smem_set = 0;
  (void)hipFuncSetAttribute((const void*)gemm_gates,
      hipFuncAttributeMaxDynamicSharedMemorySize, LDS_BYTES);
  (void)smem_set;

  cvt_x<<<M_*K_/8/256, 256, 0, stream>>>(x, xb);
  cvt_w<<<3*H_*K_/8/256, 256, 0, stream>>>(W_f, W_i, W_h, Wc);

  gemm_gates<<<NWG, 512, LDS_BYTES, stream>>>(xb, Wc, b_f, b_i, b_h, zf, zi, zh);

  scan_phaseA<<<B_*NCHUNK, 256, 0, stream>>>(zf, zi, zh, fv, Aw, Sw);
  scan_phaseB<<<B_*H_/4/256, 256, 0, stream>>>(Aw, Sw, h0, Cw);
  scan_phaseC<<<B_*NCHUNK, 256, 0, stream>>>(fv, Cw, out);
}

// Round 4
// 567.503 us; speedup vs baseline: 1.3794x; 1.1037x over previous
//
#include <hip/hip_runtime.h>
#include <hip/hip_bf16.h>
#include <stdint.h>
#include <stddef.h>

#define B_ 8
#define T_ 4096
#define D_ 1024
#define H_ 1024
#define M_ (B_*T_)      // 32768
#define K_ 1024
#define CHUNK 64
#define NCHUNK 64
#define NWGF ((M_/128)*(H_/128))   // 2048

typedef __attribute__((ext_vector_type(8))) __bf16 bf16v8;
typedef __attribute__((ext_vector_type(4))) float f32x4;
typedef __attribute__((ext_vector_type(8))) unsigned short u16x8;

// LDS (bytes): slot s at s*65536; regions per slot: A=0, Bf=16K, Bi=32K, Bh=48K.
// Each region: [row(128)][64 bf16] with st-16x32 XOR swizzle (byte ^= (row&7)<<4).
#define QA  0
#define QBF 16384
#define QBI 32768
#define QBH 49152
#define SLOT 65536
#define LDS_BYTES 131072

#define FENCE() asm volatile("" ::: "memory")
#define SBAR()  __builtin_amdgcn_s_barrier()

__device__ __forceinline__ unsigned short f2bf(float f) {
  union { float f; unsigned u; } x; x.f = f;
  return (unsigned short)((x.u + 0x7fffu + ((x.u >> 16) & 1u)) >> 16);
}

// ---------------- converts ----------------
__global__ __launch_bounds__(256) void cvt_x(const float* __restrict__ src,
                                             unsigned short* __restrict__ dst) {
  int i = blockIdx.x * 256 + threadIdx.x;      // 8 elems each
  const float4* s = (const float4*)src;
  float4 a = s[i*2], b = s[i*2+1];
  u16x8 o;
  o[0]=f2bf(a.x); o[1]=f2bf(a.y); o[2]=f2bf(a.z); o[3]=f2bf(a.w);
  o[4]=f2bf(b.x); o[5]=f2bf(b.y); o[6]=f2bf(b.z); o[7]=f2bf(b.w);
  *(u16x8*)(dst + (size_t)i*8) = o;
}

__global__ __launch_bounds__(256) void cvt_w(const float* __restrict__ w0,
                                             const float* __restrict__ w1,
                                             const float* __restrict__ w2,
                                             unsigned short* __restrict__ dst) {
  int i = blockIdx.x * 256 + threadIdx.x;      // 0..393215, 8 elems each
  int seg = i >> 17;
  int off = i & 131071;
  const float* src = (seg == 0) ? w0 : (seg == 1) ? w1 : w2;
  const float4* s = (const float4*)src;
  float4 a = s[off*2], b = s[off*2+1];
  u16x8 o;
  o[0]=f2bf(a.x); o[1]=f2bf(a.y); o[2]=f2bf(a.z); o[3]=f2bf(a.w);
  o[4]=f2bf(b.x); o[5]=f2bf(b.y); o[6]=f2bf(b.z); o[7]=f2bf(b.w);
  *(u16x8*)(dst + (size_t)i*8) = o;
}

// ---------------- fused GEMM+gates: tile 128(M)x128(H), 3 gates/WG ----------
// 8 waves (2M x 4N), wave tile 64x32 per gate. K-step 64, double-buffered.
// 3 phases/step (F,I,H). 8 stage ops/step. Counted vmcnt: 6/6/4 (tail 2/0).
__device__ __forceinline__ void stage_mat(char* lbase, const unsigned short* gbase,
                                          int k0, int tid) {
  #pragma unroll
  for (int l = 0; l < 2; ++l) {
    int o = tid*16 + l*8192;
    int row = o >> 7, cb = o & 127;
    int scb = cb ^ ((row & 7) << 4);           // pre-swizzled source (m201 pattern)
    const unsigned short* g = gbase + (size_t)row * K_ + k0 + (scb >> 1);
    __builtin_amdgcn_global_load_lds((const __attribute__((address_space(1))) void*)g,
        (__attribute__((address_space(3))) void*)(lbase + o), 16, 0, 0);
  }
}

__device__ __forceinline__ bf16v8 ldsRd(const char* base, int rr, int cb) {
  return *(const bf16v8*)(base + rr*128 + (cb ^ ((rr & 7) << 4)));
}

__device__ __forceinline__ void gate_eval(float vzf, float vzi, float vzh,
                                          float& f, float& v) {
  float spf = fmaxf(-vzf, 0.f) + __logf(1.f + __expf(-fabsf(vzf)));
  float spi = fmaxf(-vzi, 0.f) + __logf(1.f + __expf(-fabsf(vzi)));
  float d   = spf - spi;
  float l1  = __logf(1.f + __expf(-fabsf(d)));
  f = __expf(-(fmaxf(d, 0.f) + l1));
  float iv = __expf(-(fmaxf(-d, 0.f) + l1));
  float gv = (vzh >= 0.f) ? (vzh + 0.5f) : 1.f/(1.f + __expf(-vzh));
  v = iv * gv;
}

__global__ __launch_bounds__(512, 2) void gemm_fused(
    const unsigned short* __restrict__ Abf,   // [M][K] bf16
    const unsigned short* __restrict__ Wc,    // [3][H][K] bf16
    const float* __restrict__ bf_, const float* __restrict__ bi_,
    const float* __restrict__ bh_,
    uint32_t* __restrict__ fv)                // [M][H] packed {f:lo16, v:hi16}
{
  extern __shared__ char smem[];
  int tid = threadIdx.x;
  int bid = blockIdx.x;
  int swz = (bid & 7) * (NWGF/8) + (bid >> 3);  // bijective: NWGF%8==0
  int tn = swz & 7, tm = swz >> 3;
  int m0 = tm*128, n0 = tn*128;
  int lane = tid & 63, wid = tid >> 6;
  int wm = wid >> 2, wn = wid & 3;             // 2 x 4 waves
  int lr = lane & 15, lhi = lane >> 4;
  int cbL = lhi * 16;

  const unsigned short* Ag  = Abf + (size_t)m0 * K_;
  const unsigned short* BFg = Wc + (size_t)n0 * K_;
  const unsigned short* BIg = Wc + (size_t)(H_ + n0) * K_;
  const unsigned short* BHg = Wc + (size_t)(2*H_ + n0) * K_;

  f32x4 accF[4][2] = {}, accI[4][2] = {}, accH[4][2] = {};
  bf16v8 af[4][2], bF[2][2], bI[2][2], bH[2][2];

  // prologue: stage step 0 into slot 0; A,Bf must land, Bi/Bh stay in flight
  stage_mat(smem + QA,  Ag,  0, tid);
  stage_mat(smem + QBF, BFg, 0, tid);
  stage_mat(smem + QBI, BIg, 0, tid);
  stage_mat(smem + QBH, BHg, 0, tid);
  asm volatile("s_waitcnt vmcnt(4)" ::: "memory");
  SBAR(); FENCE();

  for (int t = 0; t < 16; ++t) {
    char* rd = smem + (t & 1)*SLOT;
    char* wr = smem + ((t & 1) ^ 1)*SLOT;
    int k1 = (t+1)*64;
    bool st = (t < 15);
    // ---- P0: gate F (A frags loaded here, reused in P1/P2) ----
    #pragma unroll
    for (int i = 0; i < 4; ++i)
      #pragma unroll
      for (int kk = 0; kk < 2; ++kk)
        af[i][kk] = ldsRd(rd + QA, wm*64 + i*16 + lr, kk*64 + cbL);
    #pragma unroll
    for (int j = 0; j < 2; ++j)
      #pragma unroll
      for (int kk = 0; kk < 2; ++kk)
        bF[j][kk] = ldsRd(rd + QBF, wn*32 + j*16 + lr, kk*64 + cbL);
    if (st) { stage_mat(wr + QA, Ag, k1, tid); stage_mat(wr + QBF, BFg, k1, tid); }
    FENCE();
    __builtin_amdgcn_s_setprio(1);
    #pragma unroll
    for (int i = 0; i < 4; ++i)
      #pragma unroll
      for (int j = 0; j < 2; ++j)
        #pragma unroll
        for (int kk = 0; kk < 2; ++kk)
          accF[i][j] = __builtin_amdgcn_mfma_f32_16x16x32_bf16(af[i][kk], bF[j][kk], accF[i][j], 0, 0, 0);
    __builtin_amdgcn_s_setprio(0);
    FENCE();
    // ---- P1: gate I ----
    if (st) { asm volatile("s_waitcnt vmcnt(6)" ::: "memory"); }
    else    { asm volatile("s_waitcnt vmcnt(2)" ::: "memory"); }
    SBAR(); FENCE();
    #pragma unroll
    for (int j = 0; j < 2; ++j)
      #pragma unroll
      for (int kk = 0; kk < 2; ++kk)
        bI[j][kk] = ldsRd(rd + QBI, wn*32 + j*16 + lr, kk*64 + cbL);
    if (st) stage_mat(wr + QBI, BIg, k1, tid);
    FENCE();
    __builtin_amdgcn_s_setprio(1);
    #pragma unroll
    for (int i = 0; i < 4; ++i)
      #pragma unroll
      for (int j = 0; j < 2; ++j)
        #pragma unroll
        for (int kk = 0; kk < 2; ++kk)
          accI[i][j] = __builtin_amdgcn_mfma_f32_16x16x32_bf16(af[i][kk], bI[j][kk], accI[i][j], 0, 0, 0);
    __builtin_amdgcn_s_setprio(0);
    FENCE();
    // ---- P2: gate H ----
    if (st) { asm volatile("s_waitcnt vmcnt(6)" ::: "memory"); }
    else    { asm volatile("s_waitcnt vmcnt(0)" ::: "memory"); }
    SBAR(); FENCE();
    #pragma unroll
    for (int j = 0; j < 2; ++j)
      #pragma unroll
      for (int kk = 0; kk < 2; ++kk)
        bH[j][kk] = ldsRd(rd + QBH, wn*32 + j*16 + lr, kk*64 + cbL);
    if (st) stage_mat(wr + QBH, BHg, k1, tid);
    FENCE();
    __builtin_amdgcn_s_setprio(1);
    #pragma unroll
    for (int i = 0; i < 4; ++i)
      #pragma unroll
      for (int j = 0; j < 2; ++j)
        #pragma unroll
        for (int kk = 0; kk < 2; ++kk)
          accH[i][j] = __builtin_amdgcn_mfma_f32_16x16x32_bf16(af[i][kk], bH[j][kk], accH[i][j], 0, 0, 0);
    __builtin_amdgcn_s_setprio(0);
    // ---- step end: keep next step's Bi/Bh in flight ----
    if (st) { asm volatile("s_waitcnt vmcnt(4)" ::: "memory"); SBAR(); FENCE(); }
  }

  // epilogue: gate math in-register, write packed bf16x2 {f, v}
  float bfv[2], biv[2], bhv[2];
  #pragma unroll
  for (int j = 0; j < 2; ++j) {
    int col = n0 + wn*32 + j*16 + lr;
    bfv[j] = bf_[col]; biv[j] = bi_[col]; bhv[j] = bh_[col];
  }
  #pragma unroll
  for (int i = 0; i < 4; ++i)
    #pragma unroll
    for (int j = 0; j < 2; ++j) {
      int col = n0 + wn*32 + j*16 + lr;
      int row0 = m0 + wm*64 + i*16 + lhi*4;
      #pragma unroll
      for (int r = 0; r < 4; ++r) {
        float f, v;
        gate_eval(accF[i][j][r] + bfv[j], accI[i][j][r] + biv[j],
                  accH[i][j][r] + bhv[j], f, v);
        fv[(size_t)(row0 + r)*H_ + col] =
            (uint32_t)f2bf(f) | ((uint32_t)f2bf(v) << 16);
      }
    }
}

// ---------------- phase A: per-chunk (A,S) partials from packed fv ----------
__global__ __launch_bounds__(256) void scan_phaseA(
    const uint32_t* __restrict__ fv,
    float* __restrict__ Aw, float* __restrict__ Sw)
{
  int blk = blockIdx.x;                 // 512 = b*64 + c
  int c = blk & 63, b = blk >> 6;
  int h4 = threadIdx.x * 4;
  size_t base = ((size_t)b*T_ + (size_t)c*CHUNK)*H_ + h4;
  float Ap[4] = {1.f,1.f,1.f,1.f}, S[4] = {0.f,0.f,0.f,0.f};
  for (int t = 0; t < CHUNK; ++t) {
    uint4 pk = *(const uint4*)(fv + base + (size_t)t*H_);
    uint32_t w[4] = {pk.x, pk.y, pk.z, pk.w};
    #pragma unroll
    for (int u = 0; u < 4; ++u) {
      union { uint32_t u; float f; } cf, cv;
      cf.u = (w[u] & 0xffffu) << 16;
      cv.u = w[u] & 0xffff0000u;
      S[u] = fmaf(cf.f, S[u], cv.f);
      Ap[u] *= cf.f;
    }
  }
  size_t widx = ((size_t)b*NCHUNK + c)*H_ + h4;
  *(float4*)(Aw + widx) = make_float4(Ap[0], Ap[1], Ap[2], Ap[3]);
  *(float4*)(Sw + widx) = make_float4(S[0], S[1], S[2], S[3]);
}

// ---------------- phase B: cross-chunk prefix (tiny) ------------------------
__global__ __launch_bounds__(256) void scan_phaseB(
    const float* __restrict__ Aw, const float* __restrict__ Sw,
    const float* __restrict__ h0, float* __restrict__ Cw)
{
  int i = blockIdx.x*256 + threadIdx.x;    // 0..2047
  int b = i >> 8;
  int h4 = (i & 255) * 4;
  float4 x0 = *(const float4*)(h0 + (size_t)b*H_ + h4);
  float run[4];
  const float* px = (const float*)&x0;
  #pragma unroll
  for (int u = 0; u < 4; ++u)
    run[u] = (px[u] >= 0.f) ? (px[u] + 0.5f) : 1.f/(1.f + __expf(-px[u]));
  for (int c = 0; c < NCHUNK; ++c) {
    size_t idx = ((size_t)b*NCHUNK + c)*H_ + h4;
    *(float4*)(Cw + idx) = make_float4(run[0], run[1], run[2], run[3]);
    float4 av = *(const float4*)(Aw + idx);
    float4 sv = *(const float4*)(Sw + idx);
    const float* pa = (const float*)&av;
    const float* ps = (const float*)&sv;
    #pragma unroll
    for (int u = 0; u < 4; ++u) run[u] = fmaf(pa[u], run[u], ps[u]);
  }
}

// ---------------- phase C: replay with carry, write h -----------------------
__global__ __launch_bounds__(256) void scan_phaseC(
    const uint32_t* __restrict__ fv, const float* __restrict__ Cw,
    float* __restrict__ out)
{
  int blk = blockIdx.x;
  int c = blk & 63, b = blk >> 6;
  int h4 = threadIdx.x * 4;
  float4 cw = *(const float4*)(Cw + ((size_t)b*NCHUNK + c)*H_ + h4);
  float hh[4];
  const float* pc = (const float*)&cw;
  #pragma unroll
  for (int u = 0; u < 4; ++u) hh[u] = pc[u];
  size_t base = ((size_t)b*T_ + (size_t)c*CHUNK)*H_ + h4;
  for (int t = 0; t < CHUNK; ++t) {
    size_t idx = base + (size_t)t*H_;
    uint4 pk = *(const uint4*)(fv + idx);
    uint32_t w[4] = {pk.x, pk.y, pk.z, pk.w};
    #pragma unroll
    for (int u = 0; u < 4; ++u) {
      union { uint32_t u; float f; } cf, cv;
      cf.u = (w[u] & 0xffffu) << 16;
      cv.u = w[u] & 0xffff0000u;
      hh[u] = fmaf(cf.f, hh[u], cv.f);
    }
    *(float4*)(out + idx) = make_float4(hh[0], hh[1], hh[2], hh[3]);
  }
}

extern "C" void kernel_launch(void* const* d_in, const int* in_sizes, int n_in,
                              void* d_out, int out_size, void* d_ws, size_t ws_size,
                              hipStream_t stream) {
  const float* x   = (const float*)d_in[0];
  const float* h0  = (const float*)d_in[1];
  const float* W_f = (const float*)d_in[2];
  const float* b_f = (const float*)d_in[3];
  const float* W_i = (const float*)d_in[4];
  const float* b_i = (const float*)d_in[5];
  const float* W_h = (const float*)d_in[6];
  const float* b_h = (const float*)d_in[7];
  float* out = (float*)d_out;

  char* ws = (char*)d_ws;
  unsigned short* xb = (unsigned short*)ws;                         // 67.1 MB
  unsigned short* Wc = (unsigned short*)(ws + (size_t)M_*K_*2);     // 6.3 MB
  uint32_t* fv = (uint32_t*)(ws + (size_t)M_*K_*2 + (size_t)3*H_*K_*2); // 134.2 MB
  float* Aw = (float*)(fv + (size_t)M_*H_);                         // 2 MB
  float* Sw = Aw + (size_t)B_*NCHUNK*H_;                            // 2 MB
  float* Cw = Sw + (size_t)B_*NCHUNK*H_;                            // 2 MB

  (void)hipFuncSetAttribute((const void*)gemm_fused,
      hipFuncAttributeMaxDynamicSharedMemorySize, LDS_BYTES);

  cvt_x<<<M_*K_/8/256, 256, 0, stream>>>(x, xb);
  cvt_w<<<3*H_*K_/8/256, 256, 0, stream>>>(W_f, W_i, W_h, Wc);

  gemm_fused<<<NWGF, 512, LDS_BYTES, stream>>>(xb, Wc, b_f, b_i, b_h, fv);

  scan_phaseA<<<B_*NCHUNK, 256, 0, stream>>>(fv, Aw, Sw);
  scan_phaseB<<<B_*H_/4/256, 256, 0, stream>>>(Aw, Sw, h0, Cw);
  scan_phaseC<<<B_*NCHUNK, 256, 0, stream>>>(fv, Cw, out);
}